// Round 2
// baseline (432.932 us; speedup 1.0000x reference)
//
#include <hip/hip_runtime.h>

#define HIDDEN 2048
#define NH 16
#define NKV 4
#define HD 128
#define BATCH 2
#define SEQ 2048
#define MROWS (BATCH*SEQ)          // 4096
#define NQKV (NH*HD + 2*NKV*HD)    // 3072
#define KOFF (NH*HD)               // 2048
#define VOFF (NH*HD + NKV*HD)      // 2560

typedef unsigned short u16;
typedef unsigned int u32;
typedef __bf16 bf16_t;
typedef bf16_t bf16x8 __attribute__((ext_vector_type(8)));
typedef float f32x4 __attribute__((ext_vector_type(4)));
typedef u16 u16x8 __attribute__((ext_vector_type(8)));

__device__ __forceinline__ u16 f2bf(float f) {
  u32 u = __builtin_bit_cast(u32, f);
  u32 r = (u + 0x7FFFu + ((u >> 16) & 1u)) >> 16;
  return (u16)r;
}
__device__ __forceinline__ float bf2f(u16 h) {
  u32 u = ((u32)h) << 16;
  return __builtin_bit_cast(float, u);
}

// ---------------- cast f32 -> bf16, 8 elems/thread ----------------
__global__ void cast_f32_bf16(const float* __restrict__ in, u16* __restrict__ out, int n8) {
  int i = blockIdx.x * blockDim.x + threadIdx.x;
  if (i >= n8) return;
  const float4* p = (const float4*)in + (size_t)i * 2;
  float4 a = p[0], b = p[1];
  u16x8 o;
  o[0]=f2bf(a.x); o[1]=f2bf(a.y); o[2]=f2bf(a.z); o[3]=f2bf(a.w);
  o[4]=f2bf(b.x); o[5]=f2bf(b.y); o[6]=f2bf(b.z); o[7]=f2bf(b.w);
  *((u16x8*)out + i) = o;
}

// ---------------- transpose + cast: src K x N f32 -> dst N x K bf16 ----------------
__global__ void transpose_cast(const float* __restrict__ src, u16* __restrict__ dst, int K, int N) {
  __shared__ float tile[32][33];
  int k0 = blockIdx.y * 32, n0 = blockIdx.x * 32;
  int tx = threadIdx.x, ty = threadIdx.y;
  #pragma unroll
  for (int j = 0; j < 32; j += 8)
    tile[ty + j][tx] = src[(size_t)(k0 + ty + j) * N + n0 + tx];
  __syncthreads();
  #pragma unroll
  for (int j = 0; j < 32; j += 8)
    dst[(size_t)(n0 + ty + j) * K + k0 + tx] = f2bf(tile[tx][ty + j]);
}

// ---------------- GEMM: C[M,N] = A[M,K] * Bt[N,K]^T, bf16 in, f32 acc ----------------
template<int OUT_BF16>
__global__ __launch_bounds__(256) void gemm_bt(const u16* __restrict__ A, const u16* __restrict__ Bt,
                                               void* __restrict__ Cout, int M, int N, int K) {
  __shared__ u16 As[2][128 * 32];
  __shared__ u16 Bs[2][128 * 32];
  const int tid = threadIdx.x;
  const int lane = tid & 63, wave = tid >> 6;
  const int mb = blockIdx.y * 128, nb = blockIdx.x * 128;
  const int wm = (wave >> 1) * 64, wn = (wave & 1) * 64;
  const int KT = K >> 5;

  auto stage = [&](int buf, int kt) {
    #pragma unroll
    for (int j = 0; j < 2; ++j) {
      int id0 = j * 256 + wave * 64;          // wave-uniform
      int id = id0 + lane;
      int row = id >> 2, c8 = (id & 3) * 8;
      const u16* ga = A + (size_t)(mb + row) * K + kt * 32 + c8;
      __builtin_amdgcn_global_load_lds((const __attribute__((address_space(1))) u32*)ga,
          (__attribute__((address_space(3))) u32*)&As[buf][id0 * 8], 16, 0, 0);
      const u16* gb = Bt + (size_t)(nb + row) * K + kt * 32 + c8;
      __builtin_amdgcn_global_load_lds((const __attribute__((address_space(1))) u32*)gb,
          (__attribute__((address_space(3))) u32*)&Bs[buf][id0 * 8], 16, 0, 0);
    }
  };

  f32x4 acc[4][4];
  #pragma unroll
  for (int i = 0; i < 4; ++i)
    #pragma unroll
    for (int j = 0; j < 4; ++j) acc[i][j] = (f32x4)0.0f;

  stage(0, 0);
  __syncthreads();
  for (int kt = 0; kt < KT; ++kt) {
    int cur = kt & 1;
    if (kt + 1 < KT) stage(cur ^ 1, kt + 1);
    bf16x8 af[4], bfr[4];
    #pragma unroll
    for (int mi = 0; mi < 4; ++mi) {
      int r = wm + mi * 16 + (lane & 15);
      af[mi] = __builtin_bit_cast(bf16x8, *(const u16x8*)&As[cur][r * 32 + (lane >> 4) * 8]);
    }
    #pragma unroll
    for (int ni = 0; ni < 4; ++ni) {
      int r = wn + ni * 16 + (lane & 15);
      bfr[ni] = __builtin_bit_cast(bf16x8, *(const u16x8*)&Bs[cur][r * 32 + (lane >> 4) * 8]);
    }
    #pragma unroll
    for (int mi = 0; mi < 4; ++mi)
      #pragma unroll
      for (int ni = 0; ni < 4; ++ni)
        acc[mi][ni] = __builtin_amdgcn_mfma_f32_16x16x32_bf16(af[mi], bfr[ni], acc[mi][ni], 0, 0, 0);
    __syncthreads();
  }
  // epilogue: C/D layout col = lane&15, row = (lane>>4)*4 + reg
  int rbase = mb + wm + (lane >> 4) * 4;
  int cbase = nb + wn + (lane & 15);
  #pragma unroll
  for (int mi = 0; mi < 4; ++mi) {
    #pragma unroll
    for (int r = 0; r < 4; ++r) {
      int row = rbase + mi * 16 + r;
      #pragma unroll
      for (int ni = 0; ni < 4; ++ni) {
        int col = cbase + ni * 16;
        float v = acc[mi][ni][r];
        if (OUT_BF16) ((u16*)Cout)[(size_t)row * N + col] = f2bf(v);
        else          ((float*)Cout)[(size_t)row * N + col] = v;
      }
    }
  }
}

// ---------------- RoPE in-place on QKV (bf16), Q heads 0..15, K heads 0..3 ----------------
__global__ void rope_kernel(u16* __restrict__ qkv) {
  int idx = blockIdx.x * blockDim.x + threadIdx.x;   // < MROWS*20*64
  int d = idx & 63;
  int t = idx >> 6;
  int hd = t % 20;
  int row = t / 20;
  int s = row & (SEQ - 1);
  int cb = (hd < NH) ? hd * HD : KOFF + (hd - NH) * HD;
  // inv_freq = 10000^(-d/64) ; ln(10000)/64 = 0.14391156...
  float inv = __expf((float)d * -0.14391156f);
  float freq = (float)s * inv;
  float sn = sinf(freq), cs = cosf(freq);
  size_t base = (size_t)row * NQKV + cb + d;
  float x0 = bf2f(qkv[base]), x1 = bf2f(qkv[base + 64]);
  qkv[base]      = f2bf(x0 * cs - x1 * sn);
  qkv[base + 64] = f2bf(x1 * cs + x0 * sn);
}

// ---------------- transpose V section of QKV into VT (b,kvh,d,s) ----------------
__global__ void vtrans_kernel(const u16* __restrict__ qkv, u16* __restrict__ vt) {
  __shared__ u16 tile[32][33];
  int bh = blockIdx.z;            // b*NKV + kvh
  int d0 = blockIdx.y * 32;
  int s0 = blockIdx.x * 32;
  int b = bh >> 2, kvh = bh & 3;
  int tx = threadIdx.x, ty = threadIdx.y;
  const u16* src = qkv + (size_t)(b * SEQ) * NQKV + VOFF + kvh * HD;
  #pragma unroll
  for (int j = 0; j < 32; j += 8)
    tile[ty + j][tx] = src[(size_t)(s0 + ty + j) * NQKV + d0 + tx];
  __syncthreads();
  u16* dst = vt + (size_t)bh * HD * SEQ;
  #pragma unroll
  for (int j = 0; j < 32; j += 8)
    dst[(size_t)(d0 + ty + j) * SEQ + s0 + tx] = tile[tx][ty + j];
}

// ---------------- flash attention, causal, GQA ----------------
// grid (SEQ/128, NH, B); 512 threads = 8 waves, each wave owns 16 q rows.
__global__ __launch_bounds__(512) void attn_kernel(const u16* __restrict__ qkv,
                                                   const u16* __restrict__ vt,
                                                   u16* __restrict__ out) {
  __shared__ u16 Ks[32 * 128];     // [kv][d], XOR-swizzled
  __shared__ u16 Vs[128 * 32];     // [d][kv], XOR-swizzled
  __shared__ u16 Ps[8][16 * 32];   // per-wave P tile
  const int tid = threadIdx.x, lane = tid & 63, wave = tid >> 6;
  const int qt = blockIdx.x, h = blockIdx.y, b = blockIdx.z;
  const int kvh = h >> 2;
  const int q0 = qt * 128 + wave * 16;
  const float scale = 0.08838834764831845f;  // 1/sqrt(128)

  // Q fragments, hoisted: A layout row = lane&15, k = 8*(lane>>4)+e
  bf16x8 qf[4];
  {
    const u16* qp = qkv + (size_t)(b * SEQ + q0 + (lane & 15)) * NQKV + h * HD + (lane >> 4) * 8;
    #pragma unroll
    for (int kc = 0; kc < 4; ++kc)
      qf[kc] = __builtin_bit_cast(bf16x8, *(const u16x8*)(qp + kc * 32));
  }
  f32x4 oacc[8];
  #pragma unroll
  for (int i = 0; i < 8; ++i) oacc[i] = (f32x4)0.0f;
  float mrow[4], lrow[4];
  #pragma unroll
  for (int r = 0; r < 4; ++r) { mrow[r] = -INFINITY; lrow[r] = 0.0f; }

  const int ntiles = (qt + 1) * 4;
  const u16* kbase = qkv + (size_t)(b * SEQ) * NQKV + KOFF + kvh * HD;
  const u16* vbase = vt + (size_t)(b * NKV + kvh) * HD * SEQ;

  for (int t = 0; t < ntiles; ++t) {
    int kv0 = t * 32;
    {
      // stage K tile [32][128] (swizzled): 512 thr * 8 elems
      int row = tid >> 4, c8 = (tid & 15) * 8;
      u16x8 kd = *(const u16x8*)(kbase + (size_t)(kv0 + row) * NQKV + c8);
      int byte = (row * 256 + c8 * 2) ^ ((row & 7) << 4);
      *(u16x8*)((char*)Ks + byte) = kd;
      // stage VT tile [128][32] (swizzled)
      int vrow = tid >> 2, vc8 = (tid & 3) * 8;
      u16x8 vd = *(const u16x8*)(vbase + (size_t)vrow * SEQ + kv0 + vc8);
      int vbyte = (vrow * 64 + vc8 * 2) ^ ((vrow & 3) << 4);
      *(u16x8*)((char*)Vs + vbyte) = vd;
    }
    __syncthreads();
    if (kv0 <= q0 + 15) {
      f32x4 sacc[2];
      sacc[0] = (f32x4)0.0f; sacc[1] = (f32x4)0.0f;
      #pragma unroll
      for (int n2 = 0; n2 < 2; ++n2) {
        #pragma unroll
        for (int kc = 0; kc < 4; ++kc) {
          int kvr = n2 * 16 + (lane & 15);
          int byte = (kvr * 256 + (kc * 32 + (lane >> 4) * 8) * 2) ^ ((kvr & 7) << 4);
          bf16x8 kf = __builtin_bit_cast(bf16x8, *(const u16x8*)((const char*)Ks + byte));
          sacc[n2] = __builtin_amdgcn_mfma_f32_16x16x32_bf16(qf[kc], kf, sacc[n2], 0, 0, 0);
        }
      }
      // online softmax; lane holds rows (lane>>4)*4+r, col kv0 + n2*16 + (lane&15)
      int qrow_base = q0 + (lane >> 4) * 4;
      float pv[2][4];
      #pragma unroll
      for (int r = 0; r < 4; ++r) {
        int q = qrow_base + r;
        #pragma unroll
        for (int n2 = 0; n2 < 2; ++n2) {
          int kv = kv0 + n2 * 16 + (lane & 15);
          float sv = sacc[n2][r] * scale;
          pv[n2][r] = (kv <= q) ? sv : -INFINITY;
        }
        float v = fmaxf(pv[0][r], pv[1][r]);
        v = fmaxf(v, __shfl_xor(v, 1));
        v = fmaxf(v, __shfl_xor(v, 2));
        v = fmaxf(v, __shfl_xor(v, 4));
        v = fmaxf(v, __shfl_xor(v, 8));
        float mnew = fmaxf(mrow[r], v);
        float corr = __expf(mrow[r] - mnew);
        mrow[r] = mnew;
        float psum = 0.0f;
        #pragma unroll
        for (int n2 = 0; n2 < 2; ++n2) {
          float p = __expf(pv[n2][r] - mnew);
          pv[n2][r] = p;
          psum += p;
        }
        psum += __shfl_xor(psum, 1);
        psum += __shfl_xor(psum, 2);
        psum += __shfl_xor(psum, 4);
        psum += __shfl_xor(psum, 8);
        lrow[r] = lrow[r] * corr + psum;
        #pragma unroll
        for (int nt = 0; nt < 8; ++nt) oacc[nt][r] *= corr;
      }
      // P -> LDS (C layout write), then read in A layout
      #pragma unroll
      for (int n2 = 0; n2 < 2; ++n2)
        #pragma unroll
        for (int r = 0; r < 4; ++r)
          Ps[wave][((lane >> 4) * 4 + r) * 32 + n2 * 16 + (lane & 15)] = f2bf(pv[n2][r]);
      asm volatile("s_waitcnt lgkmcnt(0)" ::: "memory");
      bf16x8 pf = __builtin_bit_cast(bf16x8, *(const u16x8*)&Ps[wave][(lane & 15) * 32 + (lane >> 4) * 8]);
      #pragma unroll
      for (int nt = 0; nt < 8; ++nt) {
        int d = nt * 16 + (lane & 15);
        int vbyte = (d * 64 + (lane >> 4) * 16) ^ ((d & 3) << 4);
        bf16x8 vf = __builtin_bit_cast(bf16x8, *(const u16x8*)((const char*)Vs + vbyte));
        oacc[nt] = __builtin_amdgcn_mfma_f32_16x16x32_bf16(pf, vf, oacc[nt], 0, 0, 0);
      }
    }
    __syncthreads();
  }
  // epilogue
  #pragma unroll
  for (int nt = 0; nt < 8; ++nt) {
    #pragma unroll
    for (int r = 0; r < 4; ++r) {
      int row = b * SEQ + q0 + (lane >> 4) * 4 + r;
      int col = h * HD + nt * 16 + (lane & 15);
      out[(size_t)row * HIDDEN + col] = f2bf(oacc[nt][r] / lrow[r]);
    }
  }
}

extern "C" void kernel_launch(void* const* d_in, const int* in_sizes, int n_in,
                              void* d_out, int out_size, void* d_ws, size_t ws_size,
                              hipStream_t stream) {
  (void)in_sizes; (void)n_in; (void)out_size; (void)ws_size;
  const float* x  = (const float*)d_in[0];
  const float* wq = (const float*)d_in[1];
  const float* wk = (const float*)d_in[2];
  const float* wv = (const float*)d_in[3];
  const float* wo = (const float*)d_in[4];
  float* out = (float*)d_out;
  char* ws = (char*)d_ws;

  u16* xbf   = (u16*)(ws);                                         // 4096x2048 bf16 (16.8MB)
  u16* wqkvt = (u16*)(ws + (size_t)16777216);                      // 3072x2048 bf16 (12.6MB)
  u16* wot   = (u16*)(ws + (size_t)16777216 + 12582912);           // 2048x2048 bf16 (8.4MB)
  u16* qkv   = (u16*)(ws + (size_t)16777216 + 12582912 + 8388608); // 4096x3072 bf16 (25.2MB)
  u16* vtb   = (u16*)(ws + (size_t)16777216 + 12582912 + 8388608 + 25165824); // 8x128x2048 (4MB)
  u16* aout  = xbf;  // alias: X no longer needed after QKV GEMM

  cast_f32_bf16<<<4096, 256, 0, stream>>>(x, xbf, MROWS * HIDDEN / 8);
  transpose_cast<<<dim3(64, 64), dim3(32, 8), 0, stream>>>(wq, wqkvt, HIDDEN, 2048);
  transpose_cast<<<dim3(16, 64), dim3(32, 8), 0, stream>>>(wk, wqkvt + (size_t)2048 * 2048, HIDDEN, 512);
  transpose_cast<<<dim3(16, 64), dim3(32, 8), 0, stream>>>(wv, wqkvt + (size_t)2560 * 2048, HIDDEN, 512);
  transpose_cast<<<dim3(64, 64), dim3(32, 8), 0, stream>>>(wo, wot, HIDDEN, HIDDEN);

  gemm_bt<1><<<dim3(NQKV / 128, MROWS / 128), 256, 0, stream>>>(xbf, wqkvt, qkv, MROWS, NQKV, HIDDEN);
  rope_kernel<<<(MROWS * 20 * 64) / 256, 256, 0, stream>>>(qkv);
  vtrans_kernel<<<dim3(SEQ / 32, HD / 32, BATCH * NKV), dim3(32, 8), 0, stream>>>(qkv, vtb);
  attn_kernel<<<dim3(SEQ / 128, NH, BATCH), 512, 0, stream>>>(qkv, vtb, aout);
  gemm_bt<0><<<dim3(HIDDEN / 128, MROWS / 128), 256, 0, stream>>>(aout, wot, out, MROWS, HIDDEN, HIDDEN);
}

// Round 4
// 375.475 us; speedup vs baseline: 1.1530x; 1.1530x over previous
//
#include <hip/hip_runtime.h>

#define HIDDEN 2048
#define NH 16
#define NKV 4
#define HD 128
#define BATCH 2
#define SEQ 2048
#define MROWS (BATCH*SEQ)          // 4096
#define NQKV (NH*HD + 2*NKV*HD)    // 3072
#define KOFF (NH*HD)               // 2048
#define VOFF (NH*HD + NKV*HD)      // 2560

typedef unsigned short u16;
typedef unsigned int u32;
typedef __bf16 bf16_t;
typedef bf16_t bf16x8 __attribute__((ext_vector_type(8)));
typedef float f32x4 __attribute__((ext_vector_type(4)));
typedef u16 u16x8 __attribute__((ext_vector_type(8)));

__device__ __forceinline__ u16 f2bf(float f) {
  u32 u = __builtin_bit_cast(u32, f);
  u32 r = (u + 0x7FFFu + ((u >> 16) & 1u)) >> 16;
  return (u16)r;
}
__device__ __forceinline__ float bf2f(u16 h) {
  u32 u = ((u32)h) << 16;
  return __builtin_bit_cast(float, u);
}

// ---------------- cast f32 -> bf16, 8 elems/thread ----------------
__global__ void cast_f32_bf16(const float* __restrict__ in, u16* __restrict__ out, int n8) {
  int i = blockIdx.x * blockDim.x + threadIdx.x;
  if (i >= n8) return;
  const float4* p = (const float4*)in + (size_t)i * 2;
  float4 a = p[0], b = p[1];
  u16x8 o;
  o[0]=f2bf(a.x); o[1]=f2bf(a.y); o[2]=f2bf(a.z); o[3]=f2bf(a.w);
  o[4]=f2bf(b.x); o[5]=f2bf(b.y); o[6]=f2bf(b.z); o[7]=f2bf(b.w);
  *((u16x8*)out + i) = o;
}

// ---------------- transpose + cast: src K x N f32 -> dst N x K bf16 ----------------
__global__ void transpose_cast(const float* __restrict__ src, u16* __restrict__ dst, int K, int N) {
  __shared__ float tile[32][33];
  int k0 = blockIdx.y * 32, n0 = blockIdx.x * 32;
  int tx = threadIdx.x, ty = threadIdx.y;
  #pragma unroll
  for (int j = 0; j < 32; j += 8)
    tile[ty + j][tx] = src[(size_t)(k0 + ty + j) * N + n0 + tx];
  __syncthreads();
  #pragma unroll
  for (int j = 0; j < 32; j += 8)
    dst[(size_t)(n0 + ty + j) * K + k0 + tx] = f2bf(tile[tx][ty + j]);
}

// ---------------- GEMM: C[M,N] = A[M,K] * Bt[N,K]^T, bf16 in, f32 acc ----------------
template<int OUT_BF16>
__global__ __launch_bounds__(256) void gemm_bt(const u16* __restrict__ A, const u16* __restrict__ Bt,
                                               void* __restrict__ Cout, int M, int N, int K) {
  __shared__ u16 As[2][128 * 32];
  __shared__ u16 Bs[2][128 * 32];
  const int tid = threadIdx.x;
  const int lane = tid & 63, wave = tid >> 6;
  const int mb = blockIdx.y * 128, nb = blockIdx.x * 128;
  const int wm = (wave >> 1) * 64, wn = (wave & 1) * 64;
  const int KT = K >> 5;

  auto stage = [&](int buf, int kt) {
    #pragma unroll
    for (int j = 0; j < 2; ++j) {
      int id0 = j * 256 + wave * 64;          // wave-uniform
      int id = id0 + lane;
      int row = id >> 2, c8 = (id & 3) * 8;
      const u16* ga = A + (size_t)(mb + row) * K + kt * 32 + c8;
      __builtin_amdgcn_global_load_lds((const __attribute__((address_space(1))) u32*)ga,
          (__attribute__((address_space(3))) u32*)&As[buf][id0 * 8], 16, 0, 0);
      const u16* gb = Bt + (size_t)(nb + row) * K + kt * 32 + c8;
      __builtin_amdgcn_global_load_lds((const __attribute__((address_space(1))) u32*)gb,
          (__attribute__((address_space(3))) u32*)&Bs[buf][id0 * 8], 16, 0, 0);
    }
  };

  f32x4 acc[4][4];
  #pragma unroll
  for (int i = 0; i < 4; ++i)
    #pragma unroll
    for (int j = 0; j < 4; ++j) acc[i][j] = (f32x4)0.0f;

  stage(0, 0);
  __syncthreads();
  for (int kt = 0; kt < KT; ++kt) {
    int cur = kt & 1;
    if (kt + 1 < KT) stage(cur ^ 1, kt + 1);
    bf16x8 af[4], bfr[4];
    #pragma unroll
    for (int mi = 0; mi < 4; ++mi) {
      int r = wm + mi * 16 + (lane & 15);
      af[mi] = __builtin_bit_cast(bf16x8, *(const u16x8*)&As[cur][r * 32 + (lane >> 4) * 8]);
    }
    #pragma unroll
    for (int ni = 0; ni < 4; ++ni) {
      int r = wn + ni * 16 + (lane & 15);
      bfr[ni] = __builtin_bit_cast(bf16x8, *(const u16x8*)&Bs[cur][r * 32 + (lane >> 4) * 8]);
    }
    #pragma unroll
    for (int mi = 0; mi < 4; ++mi)
      #pragma unroll
      for (int ni = 0; ni < 4; ++ni)
        acc[mi][ni] = __builtin_amdgcn_mfma_f32_16x16x32_bf16(af[mi], bfr[ni], acc[mi][ni], 0, 0, 0);
    __syncthreads();
  }
  // epilogue: C/D layout col = lane&15, row = (lane>>4)*4 + reg
  int rbase = mb + wm + (lane >> 4) * 4;
  int cbase = nb + wn + (lane & 15);
  #pragma unroll
  for (int mi = 0; mi < 4; ++mi) {
    #pragma unroll
    for (int r = 0; r < 4; ++r) {
      int row = rbase + mi * 16 + r;
      #pragma unroll
      for (int ni = 0; ni < 4; ++ni) {
        int col = cbase + ni * 16;
        float v = acc[mi][ni][r];
        if (OUT_BF16) ((u16*)Cout)[(size_t)row * N + col] = f2bf(v);
        else          ((float*)Cout)[(size_t)row * N + col] = v;
      }
    }
  }
}

// ---------------- RoPE in-place on QKV (bf16), Q heads 0..15, K heads 0..3 ----------------
__global__ void rope_kernel(u16* __restrict__ qkv) {
  int idx = blockIdx.x * blockDim.x + threadIdx.x;   // < MROWS*20*64
  int d = idx & 63;
  int t = idx >> 6;
  int hd = t % 20;
  int row = t / 20;
  int s = row & (SEQ - 1);
  int cb = (hd < NH) ? hd * HD : KOFF + (hd - NH) * HD;
  float inv = __expf((float)d * -0.14391156f);   // 10000^(-d/64)
  float freq = (float)s * inv;
  float sn = sinf(freq), cs = cosf(freq);
  size_t base = (size_t)row * NQKV + cb + d;
  float x0 = bf2f(qkv[base]), x1 = bf2f(qkv[base + 64]);
  qkv[base]      = f2bf(x0 * cs - x1 * sn);
  qkv[base + 64] = f2bf(x1 * cs + x0 * sn);
}

// ---------------- transpose V section of QKV into VT (b,kvh,d,s) ----------------
__global__ void vtrans_kernel(const u16* __restrict__ qkv, u16* __restrict__ vt) {
  __shared__ u16 tile[32][33];
  int bh = blockIdx.z;            // b*NKV + kvh
  int d0 = blockIdx.y * 32;
  int s0 = blockIdx.x * 32;
  int b = bh >> 2, kvh = bh & 3;
  int tx = threadIdx.x, ty = threadIdx.y;
  const u16* src = qkv + (size_t)(b * SEQ) * NQKV + VOFF + kvh * HD;
  #pragma unroll
  for (int j = 0; j < 32; j += 8)
    tile[ty + j][tx] = src[(size_t)(s0 + ty + j) * NQKV + d0 + tx];
  __syncthreads();
  u16* dst = vt + (size_t)bh * HD * SEQ;
  #pragma unroll
  for (int j = 0; j < 32; j += 8)
    dst[(size_t)(d0 + ty + j) * SEQ + s0 + tx] = tile[tx][ty + j];
}

// ---------------- flash attention, causal, GQA, paired q-tiles ----------------
// grid (8, NH, B); 512 threads = 8 waves, each wave owns 16 q rows of BOTH
// q-tile pair (qtA = blockIdx.x, qtB = 15 - blockIdx.x). KVBLK=64 tiles are
// staged once (global_load_lds, pre-swizzled source) and consumed by both
// contexts -> perfectly balanced grid (34 context-tile units per block).
__global__ __launch_bounds__(512) void attn_kernel(const u16* __restrict__ qkv,
                                                   const u16* __restrict__ vt,
                                                   u16* __restrict__ out) {
  __shared__ u16 Ks[2][64 * 128];   // [kv][d], 256B rows, chunk^=(kv&7)
  __shared__ u16 Vs[2][128 * 64];   // [d][kv], 128B rows, chunk^=(d&7)
  __shared__ u16 Ps[8][16 * 64];    // per-wave [q][kv], 128B rows, chunk^=(q&7)
  const int tid = threadIdx.x, lane = tid & 63, wave = tid >> 6;
  const int qtA = blockIdx.x, qtB = 15 - qtA;
  const int h = blockIdx.y, b = blockIdx.z;
  const int kvh = h >> 2;
  const int q0A = qtA * 128 + wave * 16;
  const int q0B = qtB * 128 + wave * 16;
  const float scale = 0.08838834764831845f;  // 1/sqrt(128)

  const u16* kbase = qkv + (size_t)(b * SEQ) * NQKV + KOFF + kvh * HD;
  const u16* vbase = vt + (size_t)(b * NKV + kvh) * HD * SEQ;

  // Q fragments for both contexts (A layout: row = lane&15, k = 8*(lane>>4)+e)
  bf16x8 qfA[4], qfB[4];
  {
    const u16* qa = qkv + (size_t)(b * SEQ + q0A + (lane & 15)) * NQKV + h * HD + (lane >> 4) * 8;
    const u16* qb = qkv + (size_t)(b * SEQ + q0B + (lane & 15)) * NQKV + h * HD + (lane >> 4) * 8;
    #pragma unroll
    for (int kc = 0; kc < 4; ++kc) {
      qfA[kc] = __builtin_bit_cast(bf16x8, *(const u16x8*)(qa + kc * 32));
      qfB[kc] = __builtin_bit_cast(bf16x8, *(const u16x8*)(qb + kc * 32));
    }
  }
  f32x4 oaccA[8], oaccB[8];
  float mA[4], lA[4], mB[4], lB[4];
  #pragma unroll
  for (int i = 0; i < 8; ++i) { oaccA[i] = (f32x4)0.0f; oaccB[i] = (f32x4)0.0f; }
  #pragma unroll
  for (int r = 0; r < 4; ++r) { mA[r] = -INFINITY; lA[r] = 0.0f; mB[r] = -INFINITY; lB[r] = 0.0f; }

  // stage tile t into buffer buf: gload_lds linear dest + inverse-swizzled src
  auto stage = [&](int buf, int t) {
    int kv0 = t * 64;
    #pragma unroll
    for (int j = 0; j < 2; ++j) {     // K: rows wave*8+j*4 + (lane>>4), chunk lane&15
      int kvr = wave * 8 + j * 4 + (lane >> 4);
      int sc = (lane & 15) ^ (kvr & 7);
      const u16* src = kbase + (size_t)(kv0 + kvr) * NQKV + sc * 8;
      __builtin_amdgcn_global_load_lds((const __attribute__((address_space(1))) u32*)src,
          (__attribute__((address_space(3))) u32*)&Ks[buf][(wave * 8 + j * 4) * 128], 16, 0, 0);
    }
    #pragma unroll
    for (int j = 0; j < 2; ++j) {     // V: rows wave*16+j*8 + (lane>>3), chunk lane&7
      int d = wave * 16 + j * 8 + (lane >> 3);
      int sc = (lane & 7) ^ (d & 7);
      const u16* src = vbase + (size_t)d * SEQ + kv0 + sc * 8;
      __builtin_amdgcn_global_load_lds((const __attribute__((address_space(1))) u32*)src,
          (__attribute__((address_space(3))) u32*)&Vs[buf][(wave * 16 + j * 8) * 64], 16, 0, 0);
    }
  };

  // one context's QK^T + online softmax (defer-max) + PV for tile at kv0
  auto do_ctx = [&](const bf16x8 (&qf)[4], f32x4 (&oacc)[8], float (&mr)[4], float (&lr)[4],
                    int q0c, int kv0, int cur) {
    f32x4 sacc[4];
    #pragma unroll
    for (int n2 = 0; n2 < 4; ++n2) sacc[n2] = (f32x4)0.0f;
    #pragma unroll
    for (int n2 = 0; n2 < 4; ++n2) {
      int kvr = n2 * 16 + (lane & 15);
      #pragma unroll
      for (int kc = 0; kc < 4; ++kc) {
        int ch = (kc * 4 + (lane >> 4)) ^ (kvr & 7);
        bf16x8 kf = __builtin_bit_cast(bf16x8, *(const u16x8*)&Ks[cur][kvr * 128 + ch * 8]);
        sacc[n2] = __builtin_amdgcn_mfma_f32_16x16x32_bf16(qf[kc], kf, sacc[n2], 0, 0, 0);
      }
    }
    // softmax: lane holds rows (lane>>4)*4+r, cols kv0 + n2*16 + (lane&15)
    u16* pwb = &Ps[wave][0];
    #pragma unroll
    for (int r = 0; r < 4; ++r) {
      int qr = (lane >> 4) * 4 + r;
      int q = q0c + qr;
      float p0, p1, p2, p3;
      {
        int kvc = kv0 + (lane & 15);
        p0 = (kvc       <= q) ? sacc[0][r] * scale : -INFINITY;
        p1 = (kvc + 16  <= q) ? sacc[1][r] * scale : -INFINITY;
        p2 = (kvc + 32  <= q) ? sacc[2][r] * scale : -INFINITY;
        p3 = (kvc + 48  <= q) ? sacc[3][r] * scale : -INFINITY;
      }
      float v = fmaxf(fmaxf(p0, p1), fmaxf(p2, p3));
      v = fmaxf(v, __shfl_xor(v, 1));
      v = fmaxf(v, __shfl_xor(v, 2));
      v = fmaxf(v, __shfl_xor(v, 4));
      v = fmaxf(v, __shfl_xor(v, 8));
      float m = mr[r];
      if (v > m + 8.0f) {            // defer-max: rescale only on real growth
        float corr = __expf(m - v);
        lr[r] *= corr;
        #pragma unroll
        for (int nt = 0; nt < 8; ++nt) oacc[nt][r] *= corr;
        m = v; mr[r] = v;
      }
      float e0 = __expf(p0 - m), e1 = __expf(p1 - m);
      float e2 = __expf(p2 - m), e3 = __expf(p3 - m);
      float ps = (e0 + e1) + (e2 + e3);
      ps += __shfl_xor(ps, 1);
      ps += __shfl_xor(ps, 2);
      ps += __shfl_xor(ps, 4);
      ps += __shfl_xor(ps, 8);
      lr[r] += ps;
      // P -> LDS at swizzled addr: row qr (128B), col n2*16+(lane&15)
      char* base = (char*)pwb + qr * 128 + (lane & 7) * 2;
      int half = (lane & 15) >> 3;
      *(u16*)(base + (((0 + half) ^ (qr & 7)) << 4)) = f2bf(e0);
      *(u16*)(base + (((2 + half) ^ (qr & 7)) << 4)) = f2bf(e1);
      *(u16*)(base + (((4 + half) ^ (qr & 7)) << 4)) = f2bf(e2);
      *(u16*)(base + (((6 + half) ^ (qr & 7)) << 4)) = f2bf(e3);
    }
    asm volatile("s_waitcnt lgkmcnt(0)" ::: "memory");
    bf16x8 pf[2];
    #pragma unroll
    for (int k2 = 0; k2 < 2; ++k2) {
      int q = lane & 15;
      int ch = (k2 * 4 + (lane >> 4)) ^ (q & 7);
      pf[k2] = __builtin_bit_cast(bf16x8, *(const u16x8*)((const char*)pwb + q * 128 + ch * 16));
    }
    #pragma unroll
    for (int nt = 0; nt < 8; ++nt) {
      int d = nt * 16 + (lane & 15);
      #pragma unroll
      for (int k2 = 0; k2 < 2; ++k2) {
        int ch = (k2 * 4 + (lane >> 4)) ^ (d & 7);
        bf16x8 vf = __builtin_bit_cast(bf16x8, *(const u16x8*)&Vs[cur][d * 64 + ch * 8]);
        oacc[nt] = __builtin_amdgcn_mfma_f32_16x16x32_bf16(pf[k2], vf, oacc[nt], 0, 0, 0);
      }
    }
  };

  const int nt_tiles = (qtB + 1) * 2;
  stage(0, 0);
  __syncthreads();
  for (int t = 0; t < nt_tiles; ++t) {
    int cur = t & 1;
    if (t + 1 < nt_tiles) stage(cur ^ 1, t + 1);
    int kv0 = t * 64;
    if (kv0 <= q0A + 15) do_ctx(qfA, oaccA, mA, lA, q0A, kv0, cur);
    if (kv0 <= q0B + 15) do_ctx(qfB, oaccB, mB, lB, q0B, kv0, cur);
    __syncthreads();
  }
  // epilogue: both contexts
  #pragma unroll
  for (int nt = 0; nt < 8; ++nt) {
    #pragma unroll
    for (int r = 0; r < 4; ++r) {
      int col = h * HD + nt * 16 + (lane & 15);
      int rowA = b * SEQ + q0A + (lane >> 4) * 4 + r;
      int rowB = b * SEQ + q0B + (lane >> 4) * 4 + r;
      out[(size_t)rowA * HIDDEN + col] = f2bf(oaccA[nt][r] / lA[r]);
      out[(size_t)rowB * HIDDEN + col] = f2bf(oaccB[nt][r] / lB[r]);
    }
  }
}

extern "C" void kernel_launch(void* const* d_in, const int* in_sizes, int n_in,
                              void* d_out, int out_size, void* d_ws, size_t ws_size,
                              hipStream_t stream) {
  (void)in_sizes; (void)n_in; (void)out_size; (void)ws_size;
  const float* x  = (const float*)d_in[0];
  const float* wq = (const float*)d_in[1];
  const float* wk = (const float*)d_in[2];
  const float* wv = (const float*)d_in[3];
  const float* wo = (const float*)d_in[4];
  float* out = (float*)d_out;
  char* ws = (char*)d_ws;

  u16* xbf   = (u16*)(ws);                                         // 4096x2048 bf16 (16.8MB)
  u16* wqkvt = (u16*)(ws + (size_t)16777216);                      // 3072x2048 bf16 (12.6MB)
  u16* wot   = (u16*)(ws + (size_t)16777216 + 12582912);           // 2048x2048 bf16 (8.4MB)
  u16* qkv   = (u16*)(ws + (size_t)16777216 + 12582912 + 8388608); // 4096x3072 bf16 (25.2MB)
  u16* vtb   = (u16*)(ws + (size_t)16777216 + 12582912 + 8388608 + 25165824); // 8x128x2048 (4MB)
  u16* aout  = xbf;  // alias: X no longer needed after QKV GEMM

  cast_f32_bf16<<<4096, 256, 0, stream>>>(x, xbf, MROWS * HIDDEN / 8);
  transpose_cast<<<dim3(64, 64), dim3(32, 8), 0, stream>>>(wq, wqkvt, HIDDEN, 2048);
  transpose_cast<<<dim3(16, 64), dim3(32, 8), 0, stream>>>(wk, wqkvt + (size_t)2048 * 2048, HIDDEN, 512);
  transpose_cast<<<dim3(16, 64), dim3(32, 8), 0, stream>>>(wv, wqkvt + (size_t)2560 * 2048, HIDDEN, 512);
  transpose_cast<<<dim3(64, 64), dim3(32, 8), 0, stream>>>(wo, wot, HIDDEN, HIDDEN);

  gemm_bt<1><<<dim3(NQKV / 128, MROWS / 128), 256, 0, stream>>>(xbf, wqkvt, qkv, MROWS, NQKV, HIDDEN);
  rope_kernel<<<(MROWS * 20 * 64) / 256, 256, 0, stream>>>(qkv);
  vtrans_kernel<<<dim3(SEQ / 32, HD / 32, BATCH * NKV), dim3(32, 8), 0, stream>>>(qkv, vtb);
  attn_kernel<<<dim3(8, NH, BATCH), 512, 0, stream>>>(qkv, vtb, aout);
  gemm_bt<0><<<dim3(HIDDEN / 128, MROWS / 128), 256, 0, stream>>>(aout, wot, out, MROWS, HIDDEN, HIDDEN);
}